// Round 1
// baseline (2252.362 us; speedup 1.0000x reference)
//
#include <hip/hip_runtime.h>
#include <math.h>

#define EPSF 1e-12f

static constexpr int B = 32, CIN = 128, COUT = 256, H = 64, W = 64;
static constexpr int HW = H * W;
static constexpr int KELEM = CIN * 9;  // 1152

// ---------------------------------------------------------------------------
// Kernel 1: normalize weights and store TRANSPOSED as wnT[(ci*9+k)][co]
// so the conv kernel can stage weights with coalesced loads.
// One block per output channel, 128 threads (thread t owns ci=t, 9 taps).
// ---------------------------------------------------------------------------
__global__ __launch_bounds__(128) void prep_w(const float* __restrict__ w,
                                              const float* __restrict__ q,
                                              float* __restrict__ wnT) {
    int co = blockIdx.x;
    int t = threadIdx.x;  // 0..127 == ci
    const float* wrow = w + co * KELEM;
    float s = 0.f;
    float v[9];
#pragma unroll
    for (int i = 0; i < 9; ++i) {
        v[i] = wrow[t * 9 + i];
        s += v[i] * v[i];
    }
    __shared__ float red[128];
    red[t] = s;
    __syncthreads();
#pragma unroll
    for (int off = 64; off > 0; off >>= 1) {
        if (t < off) red[t] += red[t + off];
        __syncthreads();
    }
    float qs = q[0] * 0.01f;
    qs = qs * qs;
    float scale = 1.f / (sqrtf(red[0]) + EPSF + qs);
#pragma unroll
    for (int i = 0; i < 9; ++i) {
        wnT[(t * 9 + i) * COUT + co] = v[i] * scale;
    }
}

// ---------------------------------------------------------------------------
// Kernel 2: s[b,y,x] = sum_ci x[b,ci,y,x]^2
// ---------------------------------------------------------------------------
__global__ __launch_bounds__(256) void chansq(const float* __restrict__ x,
                                              float* __restrict__ s) {
    int pid = blockIdx.x * 256 + threadIdx.x;  // [0, B*HW)
    int b = pid >> 12;
    int yx = pid & 4095;
    const float* xp = x + (size_t)b * CIN * HW + yx;
    float acc = 0.f;
#pragma unroll 8
    for (int ci = 0; ci < CIN; ++ci) {
        float v = xp[ci * HW];
        acc = fmaf(v, v, acc);
    }
    s[pid] = acc;
}

// ---------------------------------------------------------------------------
// Kernel 3: dinv[b,y,x] = 1 / (sqrt(box3x3(s) + eps) + q_sqr)
// ---------------------------------------------------------------------------
__global__ __launch_bounds__(256) void boxnorm(const float* __restrict__ s,
                                               const float* __restrict__ q,
                                               float* __restrict__ dinv) {
    int pid = blockIdx.x * 256 + threadIdx.x;
    int b = pid >> 12;
    int yx = pid & 4095;
    int y = yx >> 6, xc = yx & 63;
    const float* sp = s + b * HW;
    float acc = 0.f;
#pragma unroll
    for (int dy = -1; dy <= 1; ++dy) {
        int yy = y + dy;
        if (yy < 0 || yy >= H) continue;
#pragma unroll
        for (int dx = -1; dx <= 1; ++dx) {
            int xx = xc + dx;
            if (xx < 0 || xx >= W) continue;
            acc += sp[yy * W + xx];
        }
    }
    float qs = q[0] * 0.01f;
    qs = qs * qs;
    dinv[pid] = 1.f / (sqrtf(acc + EPSF) + qs);
}

// ---------------------------------------------------------------------------
// Kernel 4: main conv + epilogue.
// Block: 256 threads. Tile: batch b, couts [co0, co0+32), rows [y0, y0+8),
// all 64 cols. Thread (col = t&63, cog = t>>6) computes 8 rows x 8 couts.
// LDS: x-tile [8ci][10 rows][66 cols], w-tile [8ci][9][32 co].
// ---------------------------------------------------------------------------
__global__ __launch_bounds__(256) void scs_conv(const float* __restrict__ x,
                                                const float* __restrict__ wnT,
                                                const float* __restrict__ p,
                                                const float* __restrict__ dinv,
                                                float* __restrict__ out) {
    __shared__ float xs[8][10][66];
    __shared__ float wt[8][9][32];

    int t = threadIdx.x;
    int col = t & 63;
    int cog = t >> 6;  // 0..3, wave-uniform
    int y0 = blockIdx.x * 8;
    int co0 = blockIdx.y * 32;
    int b = blockIdx.z;

    float acc[8][8];
#pragma unroll
    for (int r = 0; r < 8; ++r)
#pragma unroll
        for (int j = 0; j < 8; ++j) acc[r][j] = 0.f;

    const float* xb = x + (size_t)b * CIN * HW;

    for (int cc = 0; cc < CIN; cc += 8) {
        // stage x tile (zero-padded halo)
        for (int idx = t; idx < 8 * 10 * 66; idx += 256) {
            int ci = idx / 660;
            int rem = idx - ci * 660;
            int row = rem / 66;
            int c = rem - row * 66;
            int gy = y0 + row - 1;
            int gx = c - 1;
            float v = 0.f;
            if (gy >= 0 && gy < H && gx >= 0 && gx < W)
                v = xb[(cc + ci) * HW + gy * W + gx];
            xs[ci][row][c] = v;
        }
        // stage weight tile (coalesced along co)
        for (int idx = t; idx < 8 * 9 * 32; idx += 256) {
            int co_l = idx & 31;
            int rk = idx >> 5;        // ci*9 + k
            int ci = rk / 9;
            int k = rk - ci * 9;
            wt[ci][k][co_l] = wnT[(cc + ci * 1) * 9 * COUT + k * COUT + co0 + co_l];
        }
        __syncthreads();

#pragma unroll 2
        for (int ci = 0; ci < 8; ++ci) {
#pragma unroll
            for (int k = 0; k < 9; ++k) {
                int ky = k / 3, kx = k - ky * 3;
                float wv[8];
#pragma unroll
                for (int j = 0; j < 8; ++j) wv[j] = wt[ci][k][cog * 8 + j];
#pragma unroll
                for (int r = 0; r < 8; ++r) {
                    float a = xs[ci][r + ky][col + kx];
#pragma unroll
                    for (int j = 0; j < 8; ++j)
                        acc[r][j] = fmaf(a, wv[j], acc[r][j]);
                }
            }
        }
        __syncthreads();
    }

    // epilogue: y = acc * dinv; out = sigmoid(y) * (|y|+eps)^((p/10)^2)
    float psq[8];
#pragma unroll
    for (int j = 0; j < 8; ++j) {
        float pv = p[co0 + cog * 8 + j] * 0.1f;
        psq[j] = pv * pv;
    }
    const float* dv = dinv + b * HW + y0 * W;
#pragma unroll
    for (int r = 0; r < 8; ++r) {
        float di = dv[r * W + col];
#pragma unroll
        for (int j = 0; j < 8; ++j) {
            float yv = acc[r][j] * di;
            float ay = fabsf(yv) + EPSF;
            float mag = powf(ay, psq[j]);
            float sg = 1.f / (1.f + expf(-yv));
            out[(((size_t)b * COUT + co0 + cog * 8 + j) * H + (y0 + r)) * W + col] =
                sg * mag;
        }
    }
}

// ---------------------------------------------------------------------------
extern "C" void kernel_launch(void* const* d_in, const int* in_sizes, int n_in,
                              void* d_out, int out_size, void* d_ws, size_t ws_size,
                              hipStream_t stream) {
    const float* x = (const float*)d_in[0];
    const float* w = (const float*)d_in[1];
    const float* p = (const float*)d_in[2];
    const float* q = (const float*)d_in[3];
    float* out = (float*)d_out;

    float* ws = (float*)d_ws;
    float* wnT = ws;                       // KELEM*COUT = 294912 floats
    float* s = wnT + KELEM * COUT;         // B*HW = 131072 floats
    float* dinv = s + B * HW;              // B*HW = 131072 floats

    prep_w<<<COUT, 128, 0, stream>>>(w, q, wnT);
    chansq<<<(B * HW) / 256, 256, 0, stream>>>(x, s);
    boxnorm<<<(B * HW) / 256, 256, 0, stream>>>(s, q, dinv);

    dim3 grid(H / 8, COUT / 32, B);
    scs_conv<<<grid, 256, 0, stream>>>(x, wnT, p, dinv, out);
}

// Round 3
// 671.552 us; speedup vs baseline: 3.3540x; 3.3540x over previous
//
#include <hip/hip_runtime.h>
#include <math.h>

#define EPSF 1e-12f

typedef __attribute__((ext_vector_type(8))) short short8;
typedef __attribute__((ext_vector_type(4))) float f32x4;
typedef __attribute__((ext_vector_type(4))) unsigned int u32x4;

static constexpr int NB = 32, CI = 128, CO = 256, H = 64, W = 64;
static constexpr int HWp = H * W;      // 4096
static constexpr int PP = 66 * 66;     // 4356 padded pixels per (b,cc) slice
// workspace layout (bytes):
//   wTe  @ 0        : 4*9*256*128      = 1,179,648   (bf16 hi/lo packed, swizzled)
//   s    @ 1179648  : 131072 f32       =   524,288
//   dinv @ 1703936  : 131072 f32       =   524,288
//   xTe  @ 2228224  : 32*4*4356*128    = 71,368,704  (+1536 B slack for tail overread)
static constexpr size_t WTE_OFF = 0;
static constexpr size_t S_OFF = 1179648;
static constexpr size_t DINV_OFF = 1703936;
static constexpr size_t XTE_OFF = 2228224;

__device__ inline void split_bf16(float v, unsigned& h, unsigned& l) {
    unsigned u = __float_as_uint(v);
    h = u >> 16;                                   // truncated bf16 hi
    float hf = __uint_as_float(h << 16);
    float lo = v - hf;
    l = __float_as_uint(lo) >> 16;                 // truncated bf16 lo
}

// ---------------------------------------------------------------------------
// prep_w: normalize weights, split hi/lo bf16, write wTe[cc][tap][co][128B]
// 128B entry = 8 blocks of 16B: blocks0-3 = hi(ci 0..31 of chunk), 4-7 = lo.
// Block index pre-swizzled: stored at (blk ^ (co&7)).
// ---------------------------------------------------------------------------
__global__ __launch_bounds__(128) void prep_w(const float* __restrict__ w,
                                              const float* __restrict__ q,
                                              unsigned short* __restrict__ wTe) {
    int co = blockIdx.x;
    int t = threadIdx.x;  // = ci
    const float* wrow = w + (size_t)co * (CI * 9);
    float v[9];
    float sacc = 0.f;
#pragma unroll
    for (int i = 0; i < 9; ++i) {
        v[i] = wrow[t * 9 + i];
        sacc += v[i] * v[i];
    }
    __shared__ float red[128];
    red[t] = sacc;
    __syncthreads();
#pragma unroll
    for (int off = 64; off > 0; off >>= 1) {
        if (t < off) red[t] += red[t + off];
        __syncthreads();
    }
    float qs = q[0] * 0.01f;
    qs = qs * qs;
    float scale = 1.f / (sqrtf(red[0]) + EPSF + qs);

    int cc = t >> 5, cil = t & 31, blk = cil >> 3, wi = cil & 7, sw = co & 7;
#pragma unroll
    for (int k = 0; k < 9; ++k) {
        float wv = v[k] * scale;
        unsigned hi, lo;
        split_bf16(wv, hi, lo);
        size_t base = ((size_t)((cc * 9 + k) * 256 + co)) * 64;  // u16 units
        wTe[base + (size_t)((blk ^ sw) * 8) + wi] = (unsigned short)hi;
        wTe[base + (size_t)(((blk + 4) ^ sw) * 8) + wi] = (unsigned short)lo;
    }
}

// ---------------------------------------------------------------------------
// prep_x: per (b,y): transpose x row to NHWC hi/lo bf16 (swizzled blocks),
// and compute s[b,y,x] = sum_ci x^2.
// ---------------------------------------------------------------------------
__global__ __launch_bounds__(256) void prep_x(const float* __restrict__ x,
                                              unsigned short* __restrict__ xTe,
                                              float* __restrict__ s) {
    __shared__ float raw[128][64];
    __shared__ float ssum[4][64];
    int y = blockIdx.x, b = blockIdx.y;
    int t = threadIdx.x;
    int g = t >> 6, px = t & 63;
    const float* xb = x + (size_t)b * CI * HWp + y * W;
    float acc = 0.f;
#pragma unroll 8
    for (int i = 0; i < 32; ++i) {
        int ci = i * 4 + g;
        float v = xb[(size_t)ci * HWp + px];
        raw[ci][px] = v;
        acc = fmaf(v, v, acc);
    }
    ssum[g][px] = acc;
    __syncthreads();
    if (t < 64)
        s[(size_t)b * HWp + y * W + t] = ssum[0][t] + ssum[1][t] + ssum[2][t] + ssum[3][t];

    // pack 128B entry for (cc=g, pixel)
    int pix = (y + 1) * 66 + (px + 1);
    unsigned hiw[16], low[16];
#pragma unroll
    for (int i = 0; i < 16; ++i) {
        unsigned h0, l0, h1, l1;
        split_bf16(raw[g * 32 + 2 * i][px], h0, l0);
        split_bf16(raw[g * 32 + 2 * i + 1][px], h1, l1);
        hiw[i] = h0 | (h1 << 16);
        low[i] = l0 | (l1 << 16);
    }
    u32x4* dst = (u32x4*)(xTe + ((size_t)(b * 4 + g) * PP + pix) * 64);
    int sw = pix & 7;
#pragma unroll
    for (int blk = 0; blk < 4; ++blk) {
        u32x4 hv = {hiw[4 * blk], hiw[4 * blk + 1], hiw[4 * blk + 2], hiw[4 * blk + 3]};
        u32x4 lv = {low[4 * blk], low[4 * blk + 1], low[4 * blk + 2], low[4 * blk + 3]};
        dst[blk ^ sw] = hv;
        dst[(blk + 4) ^ sw] = lv;
    }
}

// ---------------------------------------------------------------------------
// zero_halo: zero the padded ring pixels of xTe (260 pix per (b,cc)).
// ---------------------------------------------------------------------------
__global__ __launch_bounds__(256) void zero_halo(unsigned short* __restrict__ xTe) {
    int b = blockIdx.x, t = threadIdx.x;
    for (int sidx = t; sidx < 260 * 4 * 8; sidx += 256) {
        int pi = sidx >> 5;
        int cc = (sidx >> 3) & 3;
        int slot = sidx & 7;
        int pix;
        if (pi < 66) pix = pi;                       // top row
        else if (pi < 132) pix = 65 * 66 + (pi - 66); // bottom row
        else if (pi < 196) pix = (pi - 131) * 66;     // left col rows 1..64
        else pix = (pi - 195) * 66 + 65;              // right col rows 1..64
        u32x4 z = {0u, 0u, 0u, 0u};
        *(u32x4*)(xTe + ((size_t)(b * 4 + cc) * PP + pix) * 64 + slot * 8) = z;
    }
}

// ---------------------------------------------------------------------------
// boxnorm: dinv = 1/(sqrt(box3x3(s)+eps)+q_sqr)
// ---------------------------------------------------------------------------
__global__ __launch_bounds__(256) void boxnorm(const float* __restrict__ s,
                                               const float* __restrict__ q,
                                               float* __restrict__ dinv) {
    int pid = blockIdx.x * 256 + threadIdx.x;
    int b = pid >> 12;
    int yx = pid & 4095;
    int y = yx >> 6, xc = yx & 63;
    const float* sp = s + (size_t)b * HWp;
    float acc = 0.f;
#pragma unroll
    for (int dy = -1; dy <= 1; ++dy) {
        int yy = y + dy;
        if (yy < 0 || yy >= H) continue;
#pragma unroll
        for (int dx = -1; dx <= 1; ++dx) {
            int xx = xc + dx;
            if (xx < 0 || xx >= W) continue;
            acc += sp[yy * W + xx];
        }
    }
    float qs = q[0] * 0.01f;
    qs = qs * qs;
    dinv[pid] = 1.f / (sqrtf(acc + EPSF) + qs);
}

// ---------------------------------------------------------------------------
// scs_conv: implicit-GEMM bf16x3 MFMA conv + fused epilogue.
// Block: 512 thr / 8 waves (4M x 2N). Tile: 8 out rows x 64 cols x 128 co.
// Wave tile: 128 pixels (2 rows) x 64 co; acc = 8mf x 4nf f32x4 = 128 VGPR.
// LDS: xs 5376*16B (10 rows x 66 cols x 128B, +tail pad), ws 3 bufs x 16KB.
// ---------------------------------------------------------------------------
static constexpr int XS_BYTES = 86016;
static constexpr int WS_BYTES = 16384;

#define GLDS(gsrc, ldsoff)                                                     \
    __builtin_amdgcn_global_load_lds(                                          \
        (const __attribute__((address_space(1))) unsigned int*)(gsrc),         \
        (unsigned int __attribute__((address_space(3))) *)(smem + (ldsoff)),   \
        16, 0, 0)

__global__ __launch_bounds__(512, 2) void scs_conv(
        const unsigned short* __restrict__ xTe,
        const unsigned short* __restrict__ wTe,
        const float* __restrict__ p,
        const float* __restrict__ dinv,
        float* __restrict__ out) {
    __shared__ char smem[XS_BYTES + 3 * WS_BYTES];  // 135,168 B

    int tid = threadIdx.x;
    int lane = tid & 63, wid = tid >> 6;
    int l15 = lane & 15, l4 = lane >> 4;
    int wm = wid & 3, wn = wid >> 2;
    int oy0 = blockIdx.x * 8, coB = blockIdx.y * 128, b = blockIdx.z;

    int pixb[8];
#pragma unroll
    for (int mf = 0; mf < 8; ++mf)
        pixb[mf] = (2 * wm + (mf >> 2)) * 66 + 16 * (mf & 3) + l15;
    int boffH[4], boffL[4];
#pragma unroll
    for (int nf = 0; nf < 4; ++nf) {
        int col = wn * 64 + nf * 16 + l15;
        boffH[nf] = col * 128 + ((l4 ^ (col & 7)) * 16);
        boffL[nf] = col * 128 + (((l4 + 4) ^ (col & 7)) * 16);
    }

    f32x4 acc[8][4];
#pragma unroll
    for (int mf = 0; mf < 8; ++mf)
#pragma unroll
        for (int nf = 0; nf < 4; ++nf) acc[mf][nf] = (f32x4){0.f, 0.f, 0.f, 0.f};

#pragma unroll 1
    for (int cc = 0; cc < 4; ++cc) {
        // ---- stage x chunk: contiguous 86016 B copy (global pre-swizzled) ----
        {
            const char* src =
                (const char*)(xTe + ((size_t)(b * 4 + cc) * PP + oy0 * 66) * 64);
#pragma unroll
            for (int r = 0; r < 10; ++r) {
                int sb = r * 512 + wid * 64;
                GLDS(src + (size_t)(sb + lane) * 16, sb * 16);
            }
            if (wid < 4) {
                int sb = 5120 + wid * 64;
                GLDS(src + (size_t)(sb + lane) * 16, sb * 16);
            }
        }
        // ---- stage w tap 0 -> buf 0 ----
        {
            const char* src =
                (const char*)(wTe + ((size_t)((cc * 9 + 0) * 256 + coB)) * 64);
#pragma unroll
            for (int r = 0; r < 2; ++r) {
                int sb = r * 512 + wid * 64;
                GLDS(src + (size_t)(sb + lane) * 16, XS_BYTES + 0 * WS_BYTES + sb * 16);
            }
        }

#pragma unroll
        for (int t = 0; t < 9; ++t) {
            if (t < 8) {
                // prefetch next tap into buf (t+1)%3 (protected: readers 2 behind)
                const int nbuf = (t + 1) % 3;
                const char* src = (const char*)(wTe +
                    ((size_t)((cc * 9 + t + 1) * 256 + coB)) * 64);
#pragma unroll
                for (int r = 0; r < 2; ++r) {
                    int sb = r * 512 + wid * 64;
                    GLDS(src + (size_t)(sb + lane) * 16,
                         XS_BYTES + nbuf * WS_BYTES + sb * 16);
                }
                asm volatile("s_waitcnt vmcnt(2)" ::: "memory");
            } else {
                asm volatile("s_waitcnt vmcnt(0)" ::: "memory");
            }
            __builtin_amdgcn_s_barrier();
            asm volatile("" ::: "memory");

            const char* wb = smem + XS_BYTES + (t % 3) * WS_BYTES;
            short8 bh[4], bl[4];
#pragma unroll
            for (int nf = 0; nf < 4; ++nf) {
                bh[nf] = *(const short8*)(wb + boffH[nf]);
                bl[nf] = *(const short8*)(wb + boffL[nf]);
            }
            const int to = (t / 3) * 66 + (t % 3);  // constant-folded (t unrolled)
#pragma unroll
            for (int mf = 0; mf < 8; ++mf) {
                int pix = pixb[mf] + to;
                int sw = pix & 7;
                const char* xb = smem + pix * 128;
                short8 ah = *(const short8*)(xb + ((l4 ^ sw) * 16));
                short8 al = *(const short8*)(xb + (((l4 + 4) ^ sw) * 16));
#pragma unroll
                for (int nf = 0; nf < 4; ++nf) {
                    acc[mf][nf] = __builtin_amdgcn_mfma_f32_16x16x32_bf16(
                        ah, bh[nf], acc[mf][nf], 0, 0, 0);
                    acc[mf][nf] = __builtin_amdgcn_mfma_f32_16x16x32_bf16(
                        ah, bl[nf], acc[mf][nf], 0, 0, 0);
                    acc[mf][nf] = __builtin_amdgcn_mfma_f32_16x16x32_bf16(
                        al, bh[nf], acc[mf][nf], 0, 0, 0);
                }
            }
            asm volatile("" ::: "memory");
        }
        __builtin_amdgcn_s_barrier();  // xs reused next cc
        asm volatile("" ::: "memory");
    }

    // ---- epilogue: y = acc*dinv; out = sigmoid(y) * (|y|+eps)^psq ----
    float psq[4];
#pragma unroll
    for (int nf = 0; nf < 4; ++nf) {
        float pv = p[coB + wn * 64 + nf * 16 + l15] * 0.1f;
        psq[nf] = pv * pv;
    }
#pragma unroll
    for (int mf = 0; mf < 8; ++mf) {
        int orow = oy0 + 2 * wm + (mf >> 2);
        int ocol = 16 * (mf & 3) + l4 * 4;
        f32x4 dv = *(const f32x4*)(dinv + (size_t)b * HWp + orow * W + ocol);
#pragma unroll
        for (int nf = 0; nf < 4; ++nf) {
            int co = coB + wn * 64 + nf * 16 + l15;
            f32x4 r;
#pragma unroll
            for (int j = 0; j < 4; ++j) {
                float yv = acc[mf][nf][j] * dv[j];
                float ay = fabsf(yv) + EPSF;
                float mg = __builtin_amdgcn_exp2f(psq[nf] * __builtin_amdgcn_logf(ay));
                float sg = __builtin_amdgcn_rcpf(
                    1.0f + __builtin_amdgcn_exp2f(-1.44269504f * yv));
                r[j] = sg * mg;
            }
            *(f32x4*)(out + (((size_t)b * CO + co) * H + orow) * W + ocol) = r;
        }
    }
}

// ---------------------------------------------------------------------------
extern "C" void kernel_launch(void* const* d_in, const int* in_sizes, int n_in,
                              void* d_out, int out_size, void* d_ws, size_t ws_size,
                              hipStream_t stream) {
    (void)in_sizes; (void)n_in; (void)out_size; (void)ws_size;
    const float* x = (const float*)d_in[0];
    const float* w = (const float*)d_in[1];
    const float* p = (const float*)d_in[2];
    const float* q = (const float*)d_in[3];
    float* out = (float*)d_out;

    char* ws = (char*)d_ws;
    unsigned short* wTe = (unsigned short*)(ws + WTE_OFF);
    float* s = (float*)(ws + S_OFF);
    float* dinv = (float*)(ws + DINV_OFF);
    unsigned short* xTe = (unsigned short*)(ws + XTE_OFF);

    prep_w<<<256, 128, 0, stream>>>(w, q, wTe);
    prep_x<<<dim3(64, 32), 256, 0, stream>>>(x, xTe, s);
    zero_halo<<<32, 256, 0, stream>>>(xTe);
    boxnorm<<<(NB * HWp) / 256, 256, 0, stream>>>(s, q, dinv);

    scs_conv<<<dim3(8, 2, 32), 512, 0, stream>>>(xTe, wTe, p, dinv, out);
}

// Round 4
// 390.556 us; speedup vs baseline: 5.7671x; 1.7195x over previous
//
#include <hip/hip_runtime.h>
#include <math.h>

#define EPSF 1e-12f

typedef __attribute__((ext_vector_type(8))) short short8;
typedef __attribute__((ext_vector_type(4))) float f32x4;
typedef __attribute__((ext_vector_type(4))) unsigned int u32x4;

static constexpr int NB = 32, CI = 128, CO = 256, H = 64, W = 64;
static constexpr int HWp = H * W;      // 4096
static constexpr int PP = 66 * 66;     // 4356 padded pixels per (b,cc) slice
// workspace layout (bytes):
//   wTe  @ 0        : 4*9*256*128      = 1,179,648   (bf16 hi/lo packed, swizzled)
//   s    @ 1179648  : 131072 f32       =   524,288
//   dinv @ 1703936  : 131072 f32       =   524,288
//   xTe  @ 2228224  : 32*4*4356*128    = 71,368,704
static constexpr size_t WTE_OFF = 0;
static constexpr size_t S_OFF = 1179648;
static constexpr size_t DINV_OFF = 1703936;
static constexpr size_t XTE_OFF = 2228224;

__device__ inline void split_bf16(float v, unsigned& h, unsigned& l) {
    unsigned u = __float_as_uint(v);
    h = u >> 16;                                   // truncated bf16 hi
    float hf = __uint_as_float(h << 16);
    float lo = v - hf;
    l = __float_as_uint(lo) >> 16;                 // truncated bf16 lo
}

// ---------------------------------------------------------------------------
// prep_w: normalize weights, split hi/lo bf16, write wTe[cc][tap][co][128B]
// 128B entry = 8 blocks of 16B: blocks0-3 = hi(ci 0..31 of chunk), 4-7 = lo.
// Block index pre-swizzled: stored at (blk ^ (co&7)).
// ---------------------------------------------------------------------------
__global__ __launch_bounds__(128) void prep_w(const float* __restrict__ w,
                                              const float* __restrict__ q,
                                              unsigned short* __restrict__ wTe) {
    int co = blockIdx.x;
    int t = threadIdx.x;  // = ci
    const float* wrow = w + (size_t)co * (CI * 9);
    float v[9];
    float sacc = 0.f;
#pragma unroll
    for (int i = 0; i < 9; ++i) {
        v[i] = wrow[t * 9 + i];
        sacc += v[i] * v[i];
    }
    __shared__ float red[128];
    red[t] = sacc;
    __syncthreads();
#pragma unroll
    for (int off = 64; off > 0; off >>= 1) {
        if (t < off) red[t] += red[t + off];
        __syncthreads();
    }
    float qs = q[0] * 0.01f;
    qs = qs * qs;
    float scale = 1.f / (sqrtf(red[0]) + EPSF + qs);

    int cc = t >> 5, cil = t & 31, blk = cil >> 3, wi = cil & 7, sw = co & 7;
#pragma unroll
    for (int k = 0; k < 9; ++k) {
        float wv = v[k] * scale;
        unsigned hi, lo;
        split_bf16(wv, hi, lo);
        size_t base = ((size_t)((cc * 9 + k) * 256 + co)) * 64;  // u16 units
        wTe[base + (size_t)((blk ^ sw) * 8) + wi] = (unsigned short)hi;
        wTe[base + (size_t)(((blk + 4) ^ sw) * 8) + wi] = (unsigned short)lo;
    }
}

// ---------------------------------------------------------------------------
// prep_x: per (b,y): transpose x row to NHWC hi/lo bf16 (swizzled blocks),
// and compute s[b,y,x] = sum_ci x^2.
// ---------------------------------------------------------------------------
__global__ __launch_bounds__(256) void prep_x(const float* __restrict__ x,
                                              unsigned short* __restrict__ xTe,
                                              float* __restrict__ s) {
    __shared__ float raw[128][64];
    __shared__ float ssum[4][64];
    int y = blockIdx.x, b = blockIdx.y;
    int t = threadIdx.x;
    int g = t >> 6, px = t & 63;
    const float* xb = x + (size_t)b * CI * HWp + y * W;
    float acc = 0.f;
#pragma unroll 8
    for (int i = 0; i < 32; ++i) {
        int ci = i * 4 + g;
        float v = xb[(size_t)ci * HWp + px];
        raw[ci][px] = v;
        acc = fmaf(v, v, acc);
    }
    ssum[g][px] = acc;
    __syncthreads();
    if (t < 64)
        s[(size_t)b * HWp + y * W + t] = ssum[0][t] + ssum[1][t] + ssum[2][t] + ssum[3][t];

    // pack 128B entry for (cc=g, pixel)
    int pix = (y + 1) * 66 + (px + 1);
    unsigned hiw[16], low[16];
#pragma unroll
    for (int i = 0; i < 16; ++i) {
        unsigned h0, l0, h1, l1;
        split_bf16(raw[g * 32 + 2 * i][px], h0, l0);
        split_bf16(raw[g * 32 + 2 * i + 1][px], h1, l1);
        hiw[i] = h0 | (h1 << 16);
        low[i] = l0 | (l1 << 16);
    }
    u32x4* dst = (u32x4*)(xTe + ((size_t)(b * 4 + g) * PP + pix) * 64);
    int sw = pix & 7;
#pragma unroll
    for (int blk = 0; blk < 4; ++blk) {
        u32x4 hv = {hiw[4 * blk], hiw[4 * blk + 1], hiw[4 * blk + 2], hiw[4 * blk + 3]};
        u32x4 lv = {low[4 * blk], low[4 * blk + 1], low[4 * blk + 2], low[4 * blk + 3]};
        dst[blk ^ sw] = hv;
        dst[(blk + 4) ^ sw] = lv;
    }
}

// ---------------------------------------------------------------------------
// zero_halo: zero the padded ring pixels of xTe (260 pix per (b,cc)).
// ---------------------------------------------------------------------------
__global__ __launch_bounds__(256) void zero_halo(unsigned short* __restrict__ xTe) {
    int b = blockIdx.x, t = threadIdx.x;
    for (int sidx = t; sidx < 260 * 4 * 8; sidx += 256) {
        int pi = sidx >> 5;
        int cc = (sidx >> 3) & 3;
        int slot = sidx & 7;
        int pix;
        if (pi < 66) pix = pi;                       // top row
        else if (pi < 132) pix = 65 * 66 + (pi - 66); // bottom row
        else if (pi < 196) pix = (pi - 131) * 66;     // left col rows 1..64
        else pix = (pi - 195) * 66 + 65;              // right col rows 1..64
        u32x4 z = {0u, 0u, 0u, 0u};
        *(u32x4*)(xTe + ((size_t)(b * 4 + cc) * PP + pix) * 64 + slot * 8) = z;
    }
}

// ---------------------------------------------------------------------------
// boxnorm: dinv = 1/(sqrt(box3x3(s)+eps)+q_sqr)
// ---------------------------------------------------------------------------
__global__ __launch_bounds__(256) void boxnorm(const float* __restrict__ s,
                                               const float* __restrict__ q,
                                               float* __restrict__ dinv) {
    int pid = blockIdx.x * 256 + threadIdx.x;
    int b = pid >> 12;
    int yx = pid & 4095;
    int y = yx >> 6, xc = yx & 63;
    const float* sp = s + (size_t)b * HWp;
    float acc = 0.f;
#pragma unroll
    for (int dy = -1; dy <= 1; ++dy) {
        int yy = y + dy;
        if (yy < 0 || yy >= H) continue;
#pragma unroll
        for (int dx = -1; dx <= 1; ++dx) {
            int xx = xc + dx;
            if (xx < 0 || xx >= W) continue;
            acc += sp[yy * W + xx];
        }
    }
    float qs = q[0] * 0.01f;
    qs = qs * qs;
    dinv[pid] = 1.f / (sqrtf(acc + EPSF) + qs);
}

// ---------------------------------------------------------------------------
// scs_conv: implicit-GEMM bf16x3 MFMA conv + fused epilogue.
// Block: 256 thr / 4 waves (2M x 2N). Tile: 2 out rows x 64 cols x 128 co.
// Wave tile: 64 px (1 row) x 64 co; acc = 4mf x 4nf f32x4 = 64 VGPR.
// x in LDS (4 rows x 66 x 128B = 33.8 KB); weights direct global->VGPR,
// double-buffered one tap ahead (L2-resident, no barriers).
// 2 blocks/CU resident -> staging drains hide under the other block's MFMA.
// ---------------------------------------------------------------------------
static constexpr int XS_BYTES = 33792;   // 4*66*128
static constexpr int XS_SLOTS = 2112;    // 16B slots

#define GLDS(gsrc, ldsoff)                                                     \
    __builtin_amdgcn_global_load_lds(                                          \
        (const __attribute__((address_space(1))) unsigned int*)(gsrc),         \
        (unsigned int __attribute__((address_space(3))) *)(smem + (ldsoff)),   \
        16, 0, 0)

__global__ __launch_bounds__(256, 2) void scs_conv(
        const unsigned short* __restrict__ xTe,
        const unsigned short* __restrict__ wTe,
        const float* __restrict__ p,
        const float* __restrict__ dinv,
        float* __restrict__ out) {
    __shared__ char smem[XS_BYTES];

    int tid = threadIdx.x;
    int lane = tid & 63, wid = tid >> 6;
    int l15 = lane & 15, l4 = lane >> 4;
    int wm = wid & 1, wn = wid >> 1;
    int oy0 = blockIdx.x * 2, coB = blockIdx.y * 128, b = blockIdx.z;
    int base7 = (oy0 * 66) & 7;

    // per-lane w byte offsets within a tap's 32768B record (col&7 == l15&7)
    int woffH[4], woffL[4];
#pragma unroll
    for (int nf = 0; nf < 4; ++nf) {
        int col = coB + wn * 64 + nf * 16 + l15;
        woffH[nf] = col * 128 + ((l4 ^ (l15 & 7)) * 16);
        woffL[nf] = col * 128 + (((l4 + 4) ^ (l15 & 7)) * 16);
    }

    f32x4 acc[4][4];
#pragma unroll
    for (int mf = 0; mf < 4; ++mf)
#pragma unroll
        for (int nf = 0; nf < 4; ++nf) acc[mf][nf] = (f32x4){0.f, 0.f, 0.f, 0.f};

    short8 wh[2][4], wl[2][4];

#pragma unroll 1
    for (int cc = 0; cc < 4; ++cc) {
        __builtin_amdgcn_s_barrier();   // xs free (all waves done reading)
        // ---- stage x chunk: 33 wave-ops of 1KB (global pre-swizzled) ----
        const char* src =
            (const char*)(xTe + ((size_t)(b * 4 + cc) * PP + oy0 * 66) * 64);
#pragma unroll
        for (int k = 0; k < 9; ++k) {
            int sb = k * 256 + wid * 64;
            if (sb < XS_SLOTS) GLDS(src + (size_t)(sb + lane) * 16, sb * 16);
        }
        // ---- tap-0 weights -> regs (complete during x-drain) ----
        const char* wbase = (const char*)wTe + (size_t)cc * 9 * 32768;
#pragma unroll
        for (int nf = 0; nf < 4; ++nf) {
            wh[0][nf] = *(const short8*)(wbase + woffH[nf]);
            wl[0][nf] = *(const short8*)(wbase + woffL[nf]);
        }
        asm volatile("s_waitcnt vmcnt(0)" ::: "memory");
        __builtin_amdgcn_s_barrier();   // xs visible

#pragma unroll
        for (int t = 0; t < 9; ++t) {
            if (t < 8) {  // prefetch next tap into the other buffer
                const char* nb = wbase + (size_t)(t + 1) * 32768;
#pragma unroll
                for (int nf = 0; nf < 4; ++nf) {
                    wh[(t + 1) & 1][nf] = *(const short8*)(nb + woffH[nf]);
                    wl[(t + 1) & 1][nf] = *(const short8*)(nb + woffL[nf]);
                }
            }
            const int ty = t / 3, tx = t % 3;
#pragma unroll
            for (int mf = 0; mf < 4; ++mf) {
                int pixl = (wm + ty) * 66 + 16 * mf + l15 + tx;
                int sw = (pixl + base7) & 7;
                const char* xb = smem + pixl * 128;
                short8 ah = *(const short8*)(xb + ((l4 ^ sw) * 16));
                short8 al = *(const short8*)(xb + (((l4 + 4) ^ sw) * 16));
#pragma unroll
                for (int nf = 0; nf < 4; ++nf) {
                    acc[mf][nf] = __builtin_amdgcn_mfma_f32_16x16x32_bf16(
                        ah, wh[t & 1][nf], acc[mf][nf], 0, 0, 0);
                    acc[mf][nf] = __builtin_amdgcn_mfma_f32_16x16x32_bf16(
                        ah, wl[t & 1][nf], acc[mf][nf], 0, 0, 0);
                    acc[mf][nf] = __builtin_amdgcn_mfma_f32_16x16x32_bf16(
                        al, wh[t & 1][nf], acc[mf][nf], 0, 0, 0);
                }
            }
        }
    }

    // ---- epilogue: y = acc*dinv; out = sigmoid(y) * (|y|+eps)^psq ----
    int orow = oy0 + wm;
    float psq[4];
#pragma unroll
    for (int nf = 0; nf < 4; ++nf) {
        float pv = p[coB + wn * 64 + nf * 16 + l15] * 0.1f;
        psq[nf] = pv * pv;
    }
#pragma unroll
    for (int mf = 0; mf < 4; ++mf) {
        int ocol = 16 * mf + l4 * 4;
        f32x4 dv = *(const f32x4*)(dinv + (size_t)b * HWp + orow * W + ocol);
#pragma unroll
        for (int nf = 0; nf < 4; ++nf) {
            int co = coB + wn * 64 + nf * 16 + l15;
            f32x4 r;
#pragma unroll
            for (int j = 0; j < 4; ++j) {
                float yv = acc[mf][nf][j] * dv[j];
                float ay = fabsf(yv) + EPSF;
                float mg = __builtin_amdgcn_exp2f(psq[nf] * __builtin_amdgcn_logf(ay));
                float sg = __builtin_amdgcn_rcpf(
                    1.0f + __builtin_amdgcn_exp2f(-1.44269504f * yv));
                r[j] = sg * mg;
            }
            *(f32x4*)(out + (((size_t)b * CO + co) * H + orow) * W + ocol) = r;
        }
    }
}

// ---------------------------------------------------------------------------
extern "C" void kernel_launch(void* const* d_in, const int* in_sizes, int n_in,
                              void* d_out, int out_size, void* d_ws, size_t ws_size,
                              hipStream_t stream) {
    (void)in_sizes; (void)n_in; (void)out_size; (void)ws_size;
    const float* x = (const float*)d_in[0];
    const float* w = (const float*)d_in[1];
    const float* p = (const float*)d_in[2];
    const float* q = (const float*)d_in[3];
    float* out = (float*)d_out;

    char* ws = (char*)d_ws;
    unsigned short* wTe = (unsigned short*)(ws + WTE_OFF);
    float* s = (float*)(ws + S_OFF);
    float* dinv = (float*)(ws + DINV_OFF);
    unsigned short* xTe = (unsigned short*)(ws + XTE_OFF);

    prep_w<<<256, 128, 0, stream>>>(w, q, wTe);
    prep_x<<<dim3(64, 32), 256, 0, stream>>>(x, xTe, s);
    zero_halo<<<32, 256, 0, stream>>>(xTe);
    boxnorm<<<(NB * HWp) / 256, 256, 0, stream>>>(s, q, dinv);

    scs_conv<<<dim3(32, 2, 32), 256, 0, stream>>>(xTe, wTe, p, dinv, out);
}